// Round 3
// baseline (4128.764 us; speedup 1.0000x reference)
//
#include <hip/hip_runtime.h>
#include <math.h>

// ---------------------------------------------------------------------------
// TE-SNN forward, round 3: bit-faithful float32 emulation of the numpy ref.
//  - All dot products: single FMA chain, ascending k (BLAS microkernel order).
//  - All elementwise ops: exact numpy evaluation order via __f*_rn intrinsics
//    (blocks hipcc contraction/reassociation).
//  - ce: f32 pipeline with correctly-rounded powf/cosf (via f64 round-trip).
//  - Readout fused with atomics (osum has no feedback; ~1e-4 noise budget OK).
// Kernels: k_prep | k_ingemm (A1 = input@w1^T, no bias) | k_step x102 (skewed
// layer1(tt) / layer2(tt-1)+readout) | k_final.
// ---------------------------------------------------------------------------

#define T_STEPS 101
#define NB      512
#define INSZ    700
#define H       512
#define OUTSZ   20

__global__ __launch_bounds__(256) void k_prep(
    const float* __restrict__ wr, const float* __restrict__ w2,
    const float* __restrict__ fre,
    float* __restrict__ wrT, float* __restrict__ w2T,
    float* __restrict__ ce,
    float* __restrict__ mem1, float* __restrict__ th1,
    float* __restrict__ spb0, float* __restrict__ spb1,
    float* __restrict__ mem2, float* __restrict__ th2, float* __restrict__ sp2,
    float* __restrict__ osum)
{
  const int idx    = (int)(blockIdx.x * blockDim.x + threadIdx.x);
  const int stride = (int)(gridDim.x * blockDim.x);
  // exact transposes (copies, no rounding)
  for (int p = idx; p < H * H; p += stride) {
    const int j = p >> 9, i = p & 511;
    wrT[p] = wr[(size_t)i * H + j];
    w2T[p] = w2[(size_t)i * H + j];
  }
  // ce[t][i], faithful f32 pipeline; pow/cos correctly rounded via f64
  for (int p = idx; p < T_STEPS * H; p += stride) {
    const int t = p >> 9, i = p & 511;
    const float e   = __fdiv_rn((float)i, 512.0f);          // exact
    const float pw  = (float)pow(100.0, (double)e);          // = powf CR
    const float dtv = __fdiv_rn(0.1f, pw);
    const float fd  = __fmul_rn(fre[i], dtv);
    const float a   = __fmul_rn(fd, (float)t);
    const float cc  = (float)cos((double)a);                 // = cosf CR
    ce[p] = __fmul_rn(cc, 0.1f);
  }
  for (int p = idx; p < NB * H; p += stride) {
    mem1[p] = 0.f; th1[p] = 0.5f; spb0[p] = 0.f; spb1[p] = 0.f;
    mem2[p] = 0.f; th2[p] = 0.5f; sp2[p]  = 0.f;
  }
  for (int p = idx; p < NB * OUTSZ; p += stride) osum[p] = 0.f;
}

// A1[m][i] = sum_k input[m][k]*w1[i][k], single fma chain ascending k.
// grid (4, 404), 256 threads, 128x128 tile, BK=8, 8x8 microtile. NO bias.
__global__ __launch_bounds__(256) void k_ingemm(
    const float* __restrict__ A, const float* __restrict__ W,
    float* __restrict__ C)
{
  __shared__ float sA[8][128];
  __shared__ float sB[8][128];
  const int tid = (int)threadIdx.x;
  const int bn = (int)blockIdx.x;
  const int bm = (int)blockIdx.y;
  const int tx = tid & 15, ty = tid >> 4;
  const int lr = tid >> 1;
  const int lc = (tid & 1) * 4;
  const float* Arow = A + (size_t)(bm * 128 + lr) * INSZ;
  const float* Wrow = W + (size_t)(bn * 128 + lr) * INSZ;
  float acc[8][8];
#pragma unroll
  for (int a = 0; a < 8; ++a)
#pragma unroll
    for (int b = 0; b < 8; ++b) acc[a][b] = 0.f;

  for (int kt = 0; kt < INSZ; kt += 8) {
    const int kb = kt + lc;
    float4 av = make_float4(0.f, 0.f, 0.f, 0.f);
    float4 bv = make_float4(0.f, 0.f, 0.f, 0.f);
    if (kb < INSZ) {  // 700 % 4 == 0: float4 fully in- or out-of-bounds
      av = *reinterpret_cast<const float4*>(Arow + kb);
      bv = *reinterpret_cast<const float4*>(Wrow + kb);
    }
    __syncthreads();
    sA[lc + 0][lr] = av.x; sA[lc + 1][lr] = av.y; sA[lc + 2][lr] = av.z; sA[lc + 3][lr] = av.w;
    sB[lc + 0][lr] = bv.x; sB[lc + 1][lr] = bv.y; sB[lc + 2][lr] = bv.z; sB[lc + 3][lr] = bv.w;
    __syncthreads();
#pragma unroll
    for (int kk = 0; kk < 8; ++kk) {
      float a[8], b[8];
#pragma unroll
      for (int q = 0; q < 8; ++q) a[q] = sA[kk][ty * 8 + q];
#pragma unroll
      for (int q = 0; q < 8; ++q) b[q] = sB[kk][tx * 8 + q];
#pragma unroll
      for (int m = 0; m < 8; ++m)
#pragma unroll
        for (int n = 0; n < 8; ++n) acc[m][n] = fmaf(a[m], b[n], acc[m][n]);
    }
  }
  const int col0 = bn * 128 + tx * 8;
#pragma unroll
  for (int m = 0; m < 8; ++m) {
    float* crow = C + (size_t)(bm * 128 + ty * 8 + m) * H + col0;
#pragma unroll
    for (int q = 0; q < 8; ++q) crow[q] = acc[m][q];
  }
}

// Skewed step kernel. blockIdx.z==1: layer1(tt). z==0: layer2(tt-1)+readout.
// GEMM: 32x32 output tile, 2x2 microtile, K=512 ascending, single chain/elem.
__global__ __launch_bounds__(256) void k_step(
    const float* __restrict__ A1,
    const float* __restrict__ wrT,
    const float* __restrict__ w2T,
    const float* __restrict__ wo,
    const float* __restrict__ b1, const float* __restrict__ br,
    const float* __restrict__ b2, const float* __restrict__ bo,
    const float* __restrict__ ce,
    const float* __restrict__ spR,   // sp1 after step tt-1
    float* __restrict__ spW,         // sp1 after step tt (layer1 writes)
    float* __restrict__ mem1, float* __restrict__ th1,
    float* __restrict__ mem2, float* __restrict__ th2,
    float* __restrict__ sp2,
    float* __restrict__ osum,
    const int tt)
{
  const int z = (int)blockIdx.z;
  const int t = z ? tt : (tt - 1);
  if (z && t >= T_STEPS) return;
  if (!z && t < 0) return;

  __shared__ float sS[16][32];      // [k][n]
  __shared__ float sW[16][33];      // [k][i]
  __shared__ float lsp[32][33];     // layer2 spikes for readout

  const int tid = (int)threadIdx.x;
  const int bi  = (int)blockIdx.x;  // i-tile
  const int bn  = (int)blockIdx.y;  // n-tile
  const int tx  = tid & 15;         // i-pair index
  const int ty  = tid >> 4;         // n-pair index
  const float* WT = z ? wrT : w2T;

  float acc[2][2] = {{0.f, 0.f}, {0.f, 0.f}};

  for (int k0 = 0; k0 < H; k0 += 16) {
    __syncthreads();
#pragma unroll
    for (int pass = 0; pass < 2; ++pass) {
      const int idx = tid + pass * 256;
      const int kkS = idx & 15, nn = idx >> 4;           // nn 0..31
      sS[kkS][nn] = spR[(size_t)(bn * 32 + nn) * H + k0 + kkS];
      const int ii = idx & 31, kkW = idx >> 5;           // kkW 0..15
      sW[kkW][ii] = WT[(size_t)(k0 + kkW) * H + bi * 32 + ii];
    }
    __syncthreads();
#pragma unroll
    for (int kk = 0; kk < 16; ++kk) {
      const float a0 = sS[kk][ty * 2], a1 = sS[kk][ty * 2 + 1];
      const float b0 = sW[kk][tx * 2], b1v = sW[kk][tx * 2 + 1];
      acc[0][0] = fmaf(a0, b0,  acc[0][0]);
      acc[0][1] = fmaf(a0, b1v, acc[0][1]);
      acc[1][0] = fmaf(a1, b0,  acc[1][0]);
      acc[1][1] = fmaf(a1, b1v, acc[1][1]);
    }
  }

  const int i0 = bi * 32 + tx * 2;
  const int n0 = bn * 32 + ty * 2;
  const float* cerow = ce + (size_t)t * H;

  if (z) {
    // ---- layer 1, step t = tt ----
#pragma unroll
    for (int un = 0; un < 2; ++un) {
#pragma unroll
      for (int ui = 0; ui < 2; ++ui) {
        const int n = n0 + un, i = i0 + ui;
        const size_t p = (size_t)n * H + i;
        const float d1 = A1[((size_t)t * NB + n) * H + i];
        // h = ((d1 + b1) + d2) + br
        const float h = __fadd_rn(__fadd_rn(__fadd_rn(d1, b1[i]), acc[un][ui]), br[i]);
        const float m  = mem1[p];
        const float th = th1[p];
        const float so = spR[p];
        const float thn = __fsub_rn(__fadd_rn(th, __fmul_rn(m, cerow[i])),
                                    __fmul_rn(__fsub_rn(th, 0.5f), 0.02f));
        const float mn  = __fadd_rn(__fmul_rn(__fmul_rn(m, 0.5f), __fsub_rn(1.0f, so)), h);
        mem1[p] = mn;
        th1[p]  = thn;
        spW[p]  = (mn > thn) ? 1.0f : 0.0f;
      }
    }
  } else {
    // ---- layer 2 + readout, step t = tt-1 ----
#pragma unroll
    for (int un = 0; un < 2; ++un) {
#pragma unroll
      for (int ui = 0; ui < 2; ++ui) {
        const int n = n0 + un, i = i0 + ui;
        const size_t p = (size_t)n * H + i;
        const float h = __fadd_rn(acc[un][ui], b2[i]);
        const float m  = mem2[p];
        const float th = th2[p];
        const float so = sp2[p];
        const float thn = __fsub_rn(__fadd_rn(th, __fmul_rn(m, cerow[i])),
                                    __fmul_rn(__fsub_rn(th, 0.5f), 0.02f));
        const float mn  = __fadd_rn(__fmul_rn(__fmul_rn(m, 0.5f), __fsub_rn(1.0f, so)), h);
        const float sn  = (mn > thn) ? 1.0f : 0.0f;
        mem2[p] = mn;
        th2[p]  = thn;
        sp2[p]  = sn;
        lsp[ty * 2 + un][tx * 2 + ui] = sn;
      }
    }
    __syncthreads();
    // partial readout over this block's 32-neuron slice
    for (int pp = tid; pp < 32 * OUTSZ; pp += 256) {
      const int o   = pp >> 5;
      const int n2  = pp & 31;
      const float* worow = wo + (size_t)o * H + bi * 32;
      float s = 0.f;
#pragma unroll
      for (int jj = 0; jj < 32; ++jj) s = fmaf(lsp[n2][jj], worow[jj], s);
      if (bi == 0) s = __fadd_rn(s, bo[o]);
      atomicAdd(osum + (size_t)(bn * 32 + n2) * OUTSZ + o, s);
    }
  }
}

__global__ __launch_bounds__(256) void k_final(
    const float* __restrict__ osum, float* __restrict__ out)
{
  const int p = (int)(blockIdx.x * 256 + threadIdx.x);
  if (p < NB * OUTSZ) out[p] = __fdiv_rn(osum[p], 101.0f);
}

extern "C" void kernel_launch(void* const* d_in, const int* in_sizes, int n_in,
                              void* d_out, int out_size, void* d_ws, size_t ws_size,
                              hipStream_t stream)
{
  (void)in_sizes; (void)n_in; (void)out_size; (void)ws_size;
  const float* input = (const float*)d_in[0];
  const float* w1    = (const float*)d_in[1];
  const float* b1    = (const float*)d_in[2];
  const float* wr    = (const float*)d_in[3];
  const float* br    = (const float*)d_in[4];
  const float* w2    = (const float*)d_in[5];
  const float* b2    = (const float*)d_in[6];
  const float* wo    = (const float*)d_in[7];
  const float* bo    = (const float*)d_in[8];
  const float* fre   = (const float*)d_in[9];

  float* ws = (float*)d_ws;
  size_t off = 0;
  float* A1   = ws + off; off += (size_t)T_STEPS * NB * H;   // 26,476,544
  float* ce   = ws + off; off += (size_t)T_STEPS * H;
  float* wrT  = ws + off; off += (size_t)H * H;
  float* w2T  = ws + off; off += (size_t)H * H;
  float* mem1 = ws + off; off += (size_t)NB * H;
  float* th1  = ws + off; off += (size_t)NB * H;
  float* mem2 = ws + off; off += (size_t)NB * H;
  float* th2  = ws + off; off += (size_t)NB * H;
  float* sp2  = ws + off; off += (size_t)NB * H;
  float* spb0 = ws + off; off += (size_t)NB * H;
  float* spb1 = ws + off; off += (size_t)NB * H;
  float* osum = ws + off; off += (size_t)NB * OUTSZ;

  k_prep<<<1024, 256, 0, stream>>>(wr, w2, fre, wrT, w2T, ce,
                                   mem1, th1, spb0, spb1, mem2, th2, sp2, osum);
  k_ingemm<<<dim3(4, 404), 256, 0, stream>>>(input, w1, A1);

  for (int tt = 0; tt <= T_STEPS; ++tt) {
    float* spR = (tt & 1) ? spb0 : spb1;   // sp1 after step tt-1
    float* spW = (tt & 1) ? spb1 : spb0;   // sp1 after step tt
    k_step<<<dim3(16, 16, 2), 256, 0, stream>>>(
        A1, wrT, w2T, wo, b1, br, b2, bo, ce, spR, spW,
        mem1, th1, mem2, th2, sp2, osum, tt);
  }

  k_final<<<40, 256, 0, stream>>>(osum, (float*)d_out);
}